// Round 5
// baseline (338.760 us; speedup 1.0000x reference)
//
#include <hip/hip_runtime.h>

typedef unsigned int uint;
typedef unsigned short ushort;
typedef __attribute__((ext_vector_type(8))) short short8;
typedef __attribute__((ext_vector_type(4))) float f32x4;

__device__ __forceinline__ float b2f(ushort u) {
    return __uint_as_float(((uint)u) << 16);
}
__device__ __forceinline__ ushort f2b(float f) {
    uint u = __float_as_uint(f);
    u += 0x7FFFu + ((u >> 16) & 1u);   // round-to-nearest-even
    return (ushort)(u >> 16);
}

template<int CTRL>
__device__ __forceinline__ float dpp_add(float v) {
    int s = __float_as_int(v);
    int d = __builtin_amdgcn_update_dpp(s, s, CTRL, 0xF, 0xF, true);
    return v + __int_as_float(d);
}
// sum over 8-lane group (lanes sharing l>>3): xor1, xor2, xor7(half-mirror)
__device__ __forceinline__ float redsum8(float t) {
    t = dpp_add<0xB1>(t);    // quad_perm [1,0,3,2]  : lane ^ 1
    t = dpp_add<0x4E>(t);    // quad_perm [2,3,0,1]  : lane ^ 2
    t = dpp_add<0x141>(t);   // row_half_mirror      : lane ^ 7
    return t;
}

// ---------------------------------------------------------------------------
// GEMM: xs = x @ Wsrc + bsrc ; xd = x @ Wdst + bdst   (f32 in, f32 out)
// MFMA bf16 with x split into hi+lo bf16 (W rounded to bf16 once in LDS).
// block = 256 thr (4 waves); each block: 64 rows.
// ---------------------------------------------------------------------------
#define LDW 136

__global__ __launch_bounds__(256) void gemm_kernel(
    const float* __restrict__ x,
    const float* __restrict__ Wsrc, const float* __restrict__ bsrc,
    const float* __restrict__ Wdst, const float* __restrict__ bdst,
    float* __restrict__ xs, float* __restrict__ xd,
    int n, int* __restrict__ deg)
{
    __shared__ ushort WtS[128 * LDW];
    __shared__ ushort WtD[128 * LDW];
    int t = threadIdx.x;
    int gid = blockIdx.x * 256 + t;
    if (gid < n) deg[gid] = 1;                // self-loop contributes 1 in-degree
    for (int i = t; i < 128 * 128; i += 256) {
        int k = i >> 7, c = i & 127;
        WtS[c * LDW + k] = f2b(Wsrc[i]);      // transposed: [col][k]
        WtD[c * LDW + k] = f2b(Wdst[i]);
    }
    __syncthreads();

    int wave = t >> 6, lane = t & 63;
    int r = lane & 15, q = lane >> 4;
    int row = blockIdx.x * 64 + wave * 16 + r;      // A row this lane loads
    f32x4 accS[8], accD[8];
#pragma unroll
    for (int i = 0; i < 8; i++) { accS[i] = (f32x4)(0.f); accD[i] = (f32x4)(0.f); }

#pragma unroll
    for (int kk = 0; kk < 4; kk++) {
        float v[8];
#pragma unroll
        for (int j = 0; j < 8; j++) v[j] = 0.f;
        if (row < n) {
            const float4* src = (const float4*)(x + (long)row * 128 + kk * 32 + q * 8);
            float4 p0 = src[0], p1 = src[1];
            v[0] = p0.x; v[1] = p0.y; v[2] = p0.z; v[3] = p0.w;
            v[4] = p1.x; v[5] = p1.y; v[6] = p1.z; v[7] = p1.w;
        }
        short8 ah, al;
#pragma unroll
        for (int j = 0; j < 8; j++) {
            ushort h = f2b(v[j]);
            ah[j] = (short)h;
            al[j] = (short)f2b(v[j] - b2f(h));
        }
#pragma unroll
        for (int ct = 0; ct < 8; ct++) {
            int off = (ct * 16 + r) * LDW + kk * 32 + q * 8;
            short8 bS = *(const short8*)(WtS + off);
            short8 bD = *(const short8*)(WtD + off);
            accS[ct] = __builtin_amdgcn_mfma_f32_16x16x32_bf16(ah, bS, accS[ct], 0, 0, 0);
            accS[ct] = __builtin_amdgcn_mfma_f32_16x16x32_bf16(al, bS, accS[ct], 0, 0, 0);
            accD[ct] = __builtin_amdgcn_mfma_f32_16x16x32_bf16(ah, bD, accD[ct], 0, 0, 0);
            accD[ct] = __builtin_amdgcn_mfma_f32_16x16x32_bf16(al, bD, accD[ct], 0, 0, 0);
        }
    }
    // C/D layout: col = lane&15, row = (lane>>4)*4 + reg   [m89-verified]
    int rbase = blockIdx.x * 64 + wave * 16 + q * 4;
#pragma unroll
    for (int ct = 0; ct < 8; ct++) {
        int col = ct * 16 + r;
        float bS = bsrc[col];
        float bD = bdst[col];
#pragma unroll
        for (int rg = 0; rg < 4; rg++) {
            int orow = rbase + rg;
            if (orow < n) {
                xs[(long)orow * 128 + col] = accS[ct][rg] + bS;
                xd[(long)orow * 128 + col] = accD[ct][rg] + bD;
            }
        }
    }
}

// ---------------------------------------------------------------------------
// edge_index dtype detector: int64 (little-endian, values < 2^31 => odd 32-bit
// words all zero) vs int32. 64 lanes sample odd words 1..127.
// ---------------------------------------------------------------------------
__global__ void detect_kernel(const int* __restrict__ ei, int* __restrict__ fmt) {
    int lane = threadIdx.x;
    int w = ei[2 * lane + 1];
    unsigned long long nz = __ballot(w != 0);
    if (lane == 0) *fmt = (nz == 0ULL) ? 1 : 0;   // 1 = int64, 0 = int32
}

// ---------------------------------------------------------------------------
// CSR build
// ---------------------------------------------------------------------------
__global__ void count_kernel(const int* __restrict__ ei, int E,
                             int* __restrict__ deg, const int* __restrict__ fmt) {
    int e = blockIdx.x * 256 + threadIdx.x;
    int f = *fmt;
    if (e < E) {
        int d = f ? ei[2 * E + 2 * e] : ei[E + e];
        atomicAdd(&deg[d], 1);
    }
}

__global__ __launch_bounds__(1024) void scan_kernel(
    const int* __restrict__ deg, int* __restrict__ row_start,
    int* __restrict__ cursor, int n)
{
    __shared__ int wsum[16];
    __shared__ int wpre[16];
    int t = threadIdx.x, lane = t & 63, w = t >> 6;
    int chunk = (n + 1023) >> 10;
    int lo = t * chunk, hi = min(lo + chunk, n);
    int s = 0;
    for (int i = lo; i < hi; i++) s += deg[i];
    int inc = s;
#pragma unroll
    for (int off = 1; off < 64; off <<= 1) {
        int v = __shfl_up(inc, off);
        if (lane >= off) inc += v;
    }
    if (lane == 63) wsum[w] = inc;
    __syncthreads();
    if (t == 0) {
        int rsum = 0;
        for (int i = 0; i < 16; i++) { wpre[i] = rsum; rsum += wsum[i]; }
    }
    __syncthreads();
    int run = wpre[w] + inc - s;    // exclusive prefix for this thread's chunk
    for (int i = lo; i < hi; i++) {
        row_start[i] = run; cursor[i] = run; run += deg[i];
    }
    if (hi == n && lo < n) row_start[n] = run;
}

__global__ void fill_kernel(const int* __restrict__ ei, int E, int n,
                            int* __restrict__ cursor, int* __restrict__ esrc,
                            const int* __restrict__ fmt) {
    int idx = blockIdx.x * 256 + threadIdx.x;
    int f = *fmt;
    if (idx < E) {
        int s = f ? ei[2 * idx]         : ei[idx];
        int d = f ? ei[2 * E + 2 * idx] : ei[E + idx];
        int pos = atomicAdd(&cursor[d], 1);
        esrc[pos] = s;
    } else if (idx < E + n) {
        int i = idx - E;
        int pos = atomicAdd(&cursor[i], 1);
        esrc[pos] = i;                  // self-loop
    }
}

// ---------------------------------------------------------------------------
// Fused node kernel: one wave per dst node. Lane l owns channels (2l, 2l+1),
// both in head l>>3. Online (flash-style) segment softmax + weighted gather,
// then residual + LayerNorm + exact GELU. All f32.
// ---------------------------------------------------------------------------
__global__ __launch_bounds__(256) void node_kernel(
    const float* __restrict__ xs, const float* __restrict__ xd,
    const float* __restrict__ x,  const float* __restrict__ att,
    const float* __restrict__ bias_out, const float* __restrict__ gamma,
    const float* __restrict__ beta,
    const int* __restrict__ row_start, const int* __restrict__ esrc,
    float* __restrict__ out, int n)
{
    int lane = threadIdx.x & 63;
    int node = blockIdx.x * 4 + (threadIdx.x >> 6);
    if (node >= n) return;

    float2 dv = ((const float2*)(xd + (long)node * 128))[lane];
    float2 av = ((const float2*)att)[lane];

    int start = row_start[node], end = row_start[node + 1];
    float m = -INFINITY, s = 0.f, a0 = 0.f, a1 = 0.f;

    for (int base = start; base < end; base += 64) {
        int cnt = min(64, end - base);
        int jv = (base + lane < end) ? esrc[base + lane] : 0;
        for (int k = 0; k < cnt; k++) {
            int j = __shfl(jv, k);
            float2 sv = ((const float2*)(xs + (long)j * 128))[lane];
            float t0 = sv.x + dv.x;
            float t1 = sv.y + dv.y;
            t0 = fmaxf(t0, 0.f) + 0.2f * fminf(t0, 0.f);   // LeakyReLU(0.2)
            t1 = fmaxf(t1, 0.f) + 0.2f * fminf(t1, 0.f);
            float tt = t0 * av.x + t1 * av.y;
            float r = redsum8(tt);                          // head logit (all 8 lanes)
            // branchless online softmax update
            float mn = fmaxf(m, r);
            float cc = __expf(m - mn);
            float ee = __expf(r - mn);
            s  = s  * cc + ee;
            a0 = a0 * cc + ee * sv.x;
            a1 = a1 * cc + ee * sv.y;
            m = mn;
        }
    }

    float inv = 1.f / s;
    float2 bv = ((const float2*)bias_out)[lane];
    float2 xv = ((const float2*)(x + (long)node * 128))[lane];
    float o0 = a0 * inv + bv.x + xv.x;
    float o1 = a1 * inv + bv.y + xv.y;

    float ssum = o0 + o1, ssq = o0 * o0 + o1 * o1;
#pragma unroll
    for (int off = 32; off >= 1; off >>= 1) {
        ssum += __shfl_xor(ssum, off);
        ssq  += __shfl_xor(ssq, off);
    }
    float mean = ssum * (1.f / 128.f);
    float var  = ssq  * (1.f / 128.f) - mean * mean;
    float rstd = rsqrtf(var + 1e-5f);

    float2 gv = ((const float2*)gamma)[lane];
    float2 ev = ((const float2*)beta)[lane];
    float g0 = (o0 - mean) * rstd * gv.x + ev.x;
    float g1 = (o1 - mean) * rstd * gv.y + ev.y;
    g0 = 0.5f * g0 * (1.f + erff(g0 * 0.70710678118654752f));
    g1 = 0.5f * g1 * (1.f + erff(g1 * 0.70710678118654752f));

    float2 res; res.x = g0; res.y = g1;
    ((float2*)(out + (long)node * 128))[lane] = res;
}

// ---------------------------------------------------------------------------
extern "C" void kernel_launch(void* const* d_in, const int* in_sizes, int n_in,
                              void* d_out, int out_size, void* d_ws, size_t ws_size,
                              hipStream_t stream)
{
    const float* x    = (const float*)d_in[0];
    const int*   ei   = (const int*)d_in[1];
    const float* Wsrc = (const float*)d_in[2];
    const float* bsrc = (const float*)d_in[3];
    const float* Wdst = (const float*)d_in[4];
    const float* bdst = (const float*)d_in[5];
    const float* att  = (const float*)d_in[6];
    const float* bout = (const float*)d_in[7];
    const float* gam  = (const float*)d_in[8];
    const float* bet  = (const float*)d_in[9];
    float* out = (float*)d_out;

    int n = in_sizes[0] / 128;
    int E = in_sizes[1] / 2;

    char* p = (char*)d_ws;
    auto alloc = [&](size_t bytes) {
        char* q = p;
        p += (bytes + 255) & ~((size_t)255);
        return q;
    };
    float* xs        = (float*)alloc((size_t)n * 128 * 4);
    float* xd        = (float*)alloc((size_t)n * 128 * 4);
    int*   deg       = (int*)alloc((size_t)n * 4);
    int*   row_start = (int*)alloc((size_t)(n + 1) * 4);
    int*   cursor    = (int*)alloc((size_t)n * 4);
    int*   esrc      = (int*)alloc((size_t)(E + n) * 4);
    int*   fmt       = (int*)alloc(256);

    hipLaunchKernelGGL(detect_kernel, dim3(1), dim3(64), 0, stream, ei, fmt);
    hipLaunchKernelGGL(gemm_kernel, dim3((n + 63) / 64), dim3(256), 0, stream,
                       x, Wsrc, bsrc, Wdst, bdst, xs, xd, n, deg);
    hipLaunchKernelGGL(count_kernel, dim3((E + 255) / 256), dim3(256), 0, stream,
                       ei, E, deg, fmt);
    hipLaunchKernelGGL(scan_kernel, dim3(1), dim3(1024), 0, stream,
                       deg, row_start, cursor, n);
    hipLaunchKernelGGL(fill_kernel, dim3((E + n + 255) / 256), dim3(256), 0, stream,
                       ei, E, n, cursor, esrc, fmt);
    hipLaunchKernelGGL(node_kernel, dim3((n + 3) / 4), dim3(256), 0, stream,
                       xs, xd, x, att, bout, gam, bet, row_start, esrc, out, n);
}

// Round 7
// 254.542 us; speedup vs baseline: 1.3309x; 1.3309x over previous
//
#include <hip/hip_runtime.h>

typedef unsigned int uint;
typedef unsigned short ushort;
typedef __attribute__((ext_vector_type(8))) short short8;
typedef __attribute__((ext_vector_type(4))) float f32x4;

__device__ __forceinline__ float b2f(ushort u) {
    return __uint_as_float(((uint)u) << 16);
}
__device__ __forceinline__ ushort f2b(float f) {
    uint u = __float_as_uint(f);
    u += 0x7FFFu + ((u >> 16) & 1u);   // round-to-nearest-even
    return (ushort)(u >> 16);
}

template<int CTRL>
__device__ __forceinline__ float dpp_add(float v) {
    int s = __float_as_int(v);
    int d = __builtin_amdgcn_update_dpp(s, s, CTRL, 0xF, 0xF, true);
    return v + __int_as_float(d);
}
// sum over 8-lane group (lanes sharing l>>3): xor1, xor2, xor7(half-mirror)
__device__ __forceinline__ float redsum8(float t) {
    t = dpp_add<0xB1>(t);    // quad_perm [1,0,3,2]  : lane ^ 1
    t = dpp_add<0x4E>(t);    // quad_perm [2,3,0,1]  : lane ^ 2
    t = dpp_add<0x141>(t);   // row_half_mirror      : lane ^ 7
    return t;
}

// ---------------------------------------------------------------------------
// GEMM: xs = x @ Wsrc + bsrc ; xd = x @ Wdst + bdst   (f32 in, f32 out)
// MFMA bf16 with x split into hi+lo bf16 (W rounded to bf16 once in LDS).
// block = 256 thr (4 waves); each block: 64 rows.
// ---------------------------------------------------------------------------
#define LDW 136

__global__ __launch_bounds__(256) void gemm_kernel(
    const float* __restrict__ x,
    const float* __restrict__ Wsrc, const float* __restrict__ bsrc,
    const float* __restrict__ Wdst, const float* __restrict__ bdst,
    float* __restrict__ xs, float* __restrict__ xd,
    int n, int* __restrict__ deg)
{
    __shared__ ushort WtS[128 * LDW];
    __shared__ ushort WtD[128 * LDW];
    int t = threadIdx.x;
    int gid = blockIdx.x * 256 + t;
    if (gid < n) deg[gid] = 1;                // self-loop contributes 1 in-degree
    for (int i = t; i < 128 * 128; i += 256) {
        int k = i >> 7, c = i & 127;
        WtS[c * LDW + k] = f2b(Wsrc[i]);      // transposed: [col][k]
        WtD[c * LDW + k] = f2b(Wdst[i]);
    }
    __syncthreads();

    int wave = t >> 6, lane = t & 63;
    int r = lane & 15, q = lane >> 4;
    int row = blockIdx.x * 64 + wave * 16 + r;      // A row this lane loads
    f32x4 accS[8], accD[8];
#pragma unroll
    for (int i = 0; i < 8; i++) { accS[i] = (f32x4)(0.f); accD[i] = (f32x4)(0.f); }

#pragma unroll
    for (int kk = 0; kk < 4; kk++) {
        float v[8];
#pragma unroll
        for (int j = 0; j < 8; j++) v[j] = 0.f;
        if (row < n) {
            const float4* src = (const float4*)(x + (long)row * 128 + kk * 32 + q * 8);
            float4 p0 = src[0], p1 = src[1];
            v[0] = p0.x; v[1] = p0.y; v[2] = p0.z; v[3] = p0.w;
            v[4] = p1.x; v[5] = p1.y; v[6] = p1.z; v[7] = p1.w;
        }
        short8 ah, al;
#pragma unroll
        for (int j = 0; j < 8; j++) {
            ushort h = f2b(v[j]);
            ah[j] = (short)h;
            al[j] = (short)f2b(v[j] - b2f(h));
        }
#pragma unroll
        for (int ct = 0; ct < 8; ct++) {
            int off = (ct * 16 + r) * LDW + kk * 32 + q * 8;
            short8 bS = *(const short8*)(WtS + off);
            short8 bD = *(const short8*)(WtD + off);
            accS[ct] = __builtin_amdgcn_mfma_f32_16x16x32_bf16(ah, bS, accS[ct], 0, 0, 0);
            accS[ct] = __builtin_amdgcn_mfma_f32_16x16x32_bf16(al, bS, accS[ct], 0, 0, 0);
            accD[ct] = __builtin_amdgcn_mfma_f32_16x16x32_bf16(ah, bD, accD[ct], 0, 0, 0);
            accD[ct] = __builtin_amdgcn_mfma_f32_16x16x32_bf16(al, bD, accD[ct], 0, 0, 0);
        }
    }
    // C/D layout: col = lane&15, row = (lane>>4)*4 + reg   [m89-verified]
    int rbase = blockIdx.x * 64 + wave * 16 + q * 4;
#pragma unroll
    for (int ct = 0; ct < 8; ct++) {
        int col = ct * 16 + r;
        float bS = bsrc[col];
        float bD = bdst[col];
#pragma unroll
        for (int rg = 0; rg < 4; rg++) {
            int orow = rbase + rg;
            if (orow < n) {
                xs[(long)orow * 128 + col] = accS[ct][rg] + bS;
                xd[(long)orow * 128 + col] = accD[ct][rg] + bD;
            }
        }
    }
}

// ---------------------------------------------------------------------------
// edge_index dtype detector: int64 (little-endian, values < 2^31 => odd 32-bit
// words all zero) vs int32. 64 lanes sample odd words 1..127.
// ---------------------------------------------------------------------------
__global__ void detect_kernel(const int* __restrict__ ei, int* __restrict__ fmt) {
    int lane = threadIdx.x;
    int w = ei[2 * lane + 1];
    unsigned long long nz = __ballot(w != 0);
    if (lane == 0) *fmt = (nz == 0ULL) ? 1 : 0;   // 1 = int64, 0 = int32
}

// ---------------------------------------------------------------------------
// CSR build
// ---------------------------------------------------------------------------
__global__ void count_kernel(const int* __restrict__ ei, int E,
                             int* __restrict__ deg, const int* __restrict__ fmt) {
    int e = blockIdx.x * 256 + threadIdx.x;
    int f = *fmt;
    if (e < E) {
        int d = f ? ei[2 * E + 2 * e] : ei[E + e];
        atomicAdd(&deg[d], 1);
    }
}

// Parallel scan, pass 1: block-local exclusive scan of deg.
// lpre[g] = exclusive prefix within block; bsum[b] = block total.
__global__ __launch_bounds__(1024) void scan_blk(
    const int* __restrict__ deg, int* __restrict__ lpre,
    int* __restrict__ bsum, int n)
{
    __shared__ int ws[16];
    __shared__ int wp[16];
    int t = threadIdx.x, lane = t & 63, w = t >> 6;
    int g = blockIdx.x * 1024 + t;
    int v = (g < n) ? deg[g] : 0;
    int inc = v;
#pragma unroll
    for (int off = 1; off < 64; off <<= 1) {
        int sh = __shfl_up(inc, off);
        if (lane >= off) inc += sh;
    }
    if (lane == 63) ws[w] = inc;
    __syncthreads();
    if (t == 0) {
        int run = 0;
#pragma unroll
        for (int i = 0; i < 16; i++) { wp[i] = run; run += ws[i]; }
        bsum[blockIdx.x] = run;
    }
    __syncthreads();
    if (g < n) lpre[g] = wp[w] + inc - v;
}

// Parallel scan, pass 2: add preceding block totals, emit row_start + cursor.
__global__ __launch_bounds__(1024) void scan_fix(
    const int* __restrict__ lpre, const int* __restrict__ bsum,
    const int* __restrict__ deg, int* __restrict__ row_start,
    int* __restrict__ cursor, int n)
{
    __shared__ int boff_s;
    int t = threadIdx.x, b = blockIdx.x;
    if (t < 64) {
        int v = 0;
        for (int i = t; i < b; i += 64) v += bsum[i];
#pragma unroll
        for (int off = 32; off >= 1; off >>= 1) v += __shfl_xor(v, off);
        if (t == 0) boff_s = v;
    }
    __syncthreads();
    int g = b * 1024 + t;
    if (g < n) {
        int rs = lpre[g] + boff_s;
        row_start[g] = rs;
        cursor[g] = rs;
        if (g == n - 1) row_start[n] = rs + deg[g];
    }
}

__global__ void fill_kernel(const int* __restrict__ ei, int E, int n,
                            int* __restrict__ cursor, int* __restrict__ esrc,
                            const int* __restrict__ fmt) {
    int idx = blockIdx.x * 256 + threadIdx.x;
    int f = *fmt;
    if (idx < E) {
        int s = f ? ei[2 * idx]         : ei[idx];
        int d = f ? ei[2 * E + 2 * idx] : ei[E + idx];
        int pos = atomicAdd(&cursor[d], 1);
        esrc[pos] = s;
    } else if (idx < E + n) {
        int i = idx - E;
        int pos = atomicAdd(&cursor[i], 1);
        esrc[pos] = i;                  // self-loop
    }
}

// ---------------------------------------------------------------------------
// Fused node kernel: one wave per dst node. Lane l owns channels (2l, 2l+1),
// both in head l>>3. Online (flash-style) segment softmax + weighted gather,
// then residual + LayerNorm + exact GELU. All f32.
// ---------------------------------------------------------------------------
__global__ __launch_bounds__(256) void node_kernel(
    const float* __restrict__ xs, const float* __restrict__ xd,
    const float* __restrict__ x,  const float* __restrict__ att,
    const float* __restrict__ bias_out, const float* __restrict__ gamma,
    const float* __restrict__ beta,
    const int* __restrict__ row_start, const int* __restrict__ esrc,
    float* __restrict__ out, int n)
{
    int lane = threadIdx.x & 63;
    int node = blockIdx.x * 4 + (threadIdx.x >> 6);
    if (node >= n) return;

    float2 dv = ((const float2*)(xd + (long)node * 128))[lane];
    float2 av = ((const float2*)att)[lane];

    int start = row_start[node], end = row_start[node + 1];
    float m = -INFINITY, s = 0.f, a0 = 0.f, a1 = 0.f;

    for (int base = start; base < end; base += 64) {
        int cnt = min(64, end - base);
        int jv = (base + lane < end) ? esrc[base + lane] : 0;
        for (int k = 0; k < cnt; k++) {
            int j = __shfl(jv, k);
            float2 sv = ((const float2*)(xs + (long)j * 128))[lane];
            float t0 = sv.x + dv.x;
            float t1 = sv.y + dv.y;
            t0 = fmaxf(t0, 0.f) + 0.2f * fminf(t0, 0.f);   // LeakyReLU(0.2)
            t1 = fmaxf(t1, 0.f) + 0.2f * fminf(t1, 0.f);
            float tt = t0 * av.x + t1 * av.y;
            float r = redsum8(tt);                          // head logit (all 8 lanes)
            // branchless online softmax update
            float mn = fmaxf(m, r);
            float cc = __expf(m - mn);
            float ee = __expf(r - mn);
            s  = s  * cc + ee;
            a0 = a0 * cc + ee * sv.x;
            a1 = a1 * cc + ee * sv.y;
            m = mn;
        }
    }

    float inv = 1.f / s;
    float2 bv = ((const float2*)bias_out)[lane];
    float2 xv = ((const float2*)(x + (long)node * 128))[lane];
    float o0 = a0 * inv + bv.x + xv.x;
    float o1 = a1 * inv + bv.y + xv.y;

    float ssum = o0 + o1, ssq = o0 * o0 + o1 * o1;
#pragma unroll
    for (int off = 32; off >= 1; off >>= 1) {
        ssum += __shfl_xor(ssum, off);
        ssq  += __shfl_xor(ssq, off);
    }
    float mean = ssum * (1.f / 128.f);
    float var  = ssq  * (1.f / 128.f) - mean * mean;
    float rstd = rsqrtf(var + 1e-5f);

    float2 gv = ((const float2*)gamma)[lane];
    float2 ev = ((const float2*)beta)[lane];
    float g0 = (o0 - mean) * rstd * gv.x + ev.x;
    float g1 = (o1 - mean) * rstd * gv.y + ev.y;
    g0 = 0.5f * g0 * (1.f + erff(g0 * 0.70710678118654752f));
    g1 = 0.5f * g1 * (1.f + erff(g1 * 0.70710678118654752f));

    float2 res; res.x = g0; res.y = g1;
    ((float2*)(out + (long)node * 128))[lane] = res;
}

// ---------------------------------------------------------------------------
extern "C" void kernel_launch(void* const* d_in, const int* in_sizes, int n_in,
                              void* d_out, int out_size, void* d_ws, size_t ws_size,
                              hipStream_t stream)
{
    const float* x    = (const float*)d_in[0];
    const int*   ei   = (const int*)d_in[1];
    const float* Wsrc = (const float*)d_in[2];
    const float* bsrc = (const float*)d_in[3];
    const float* Wdst = (const float*)d_in[4];
    const float* bdst = (const float*)d_in[5];
    const float* att  = (const float*)d_in[6];
    const float* bout = (const float*)d_in[7];
    const float* gam  = (const float*)d_in[8];
    const float* bet  = (const float*)d_in[9];
    float* out = (float*)d_out;

    int n = in_sizes[0] / 128;
    int E = in_sizes[1] / 2;

    char* p = (char*)d_ws;
    auto alloc = [&](size_t bytes) {
        char* q = p;
        p += (bytes + 255) & ~((size_t)255);
        return q;
    };
    float* xs        = (float*)alloc((size_t)n * 128 * 4);
    float* xd        = (float*)alloc((size_t)n * 128 * 4);
    int*   deg       = (int*)alloc((size_t)n * 4);
    int*   row_start = (int*)alloc((size_t)(n + 1) * 4);
    int*   cursor    = (int*)alloc((size_t)n * 4);
    int*   esrc      = (int*)alloc((size_t)(E + n) * 4);
    int*   fmt       = (int*)alloc(256);
    int    nblk      = (n + 1023) / 1024;
    int*   lpre      = (int*)alloc((size_t)nblk * 1024 * 4);
    int*   bsum      = (int*)alloc((size_t)nblk * 4);

    hipLaunchKernelGGL(detect_kernel, dim3(1), dim3(64), 0, stream, ei, fmt);
    hipLaunchKernelGGL(gemm_kernel, dim3((n + 63) / 64), dim3(256), 0, stream,
                       x, Wsrc, bsrc, Wdst, bdst, xs, xd, n, deg);
    hipLaunchKernelGGL(count_kernel, dim3((E + 255) / 256), dim3(256), 0, stream,
                       ei, E, deg, fmt);
    hipLaunchKernelGGL(scan_blk, dim3(nblk), dim3(1024), 0, stream,
                       deg, lpre, bsum, n);
    hipLaunchKernelGGL(scan_fix, dim3(nblk), dim3(1024), 0, stream,
                       lpre, bsum, deg, row_start, cursor, n);
    hipLaunchKernelGGL(fill_kernel, dim3((E + n + 255) / 256), dim3(256), 0, stream,
                       ei, E, n, cursor, esrc, fmt);
    hipLaunchKernelGGL(node_kernel, dim3((n + 3) / 4), dim3(256), 0, stream,
                       xs, xd, x, att, bout, gam, bet, row_start, esrc, out, n);
}

// Round 8
// 250.018 us; speedup vs baseline: 1.3549x; 1.0181x over previous
//
#include <hip/hip_runtime.h>

typedef unsigned int uint;
typedef unsigned short ushort;
typedef __attribute__((ext_vector_type(8))) short short8;
typedef __attribute__((ext_vector_type(4))) float f32x4;

__device__ __forceinline__ float b2f(ushort u) {
    return __uint_as_float(((uint)u) << 16);
}
__device__ __forceinline__ ushort f2b(float f) {
    uint u = __float_as_uint(f);
    u += 0x7FFFu + ((u >> 16) & 1u);   // round-to-nearest-even
    return (ushort)(u >> 16);
}

template<int CTRL>
__device__ __forceinline__ float dpp_add(float v) {
    int s = __float_as_int(v);
    int d = __builtin_amdgcn_update_dpp(s, s, CTRL, 0xF, 0xF, true);
    return v + __int_as_float(d);
}
// sum over 8-lane group (lanes sharing l>>3): xor1, xor2, xor7(half-mirror)
__device__ __forceinline__ float redsum8(float t) {
    t = dpp_add<0xB1>(t);    // quad_perm [1,0,3,2]  : lane ^ 1
    t = dpp_add<0x4E>(t);    // quad_perm [2,3,0,1]  : lane ^ 2
    t = dpp_add<0x141>(t);   // row_half_mirror      : lane ^ 7
    return t;
}

// ---------------------------------------------------------------------------
// GEMM: xs = x @ Wsrc + bsrc ; xd = x @ Wdst + bdst   (f32 in, f32 out)
// MFMA bf16 with x split into hi+lo bf16 (W rounded to bf16 once in LDS).
// block = 256 thr (4 waves); each block: 64 rows.
// ---------------------------------------------------------------------------
#define LDW 136

__global__ __launch_bounds__(256) void gemm_kernel(
    const float* __restrict__ x,
    const float* __restrict__ Wsrc, const float* __restrict__ bsrc,
    const float* __restrict__ Wdst, const float* __restrict__ bdst,
    float* __restrict__ xs, float* __restrict__ xd,
    int n, int* __restrict__ deg)
{
    __shared__ ushort WtS[128 * LDW];
    __shared__ ushort WtD[128 * LDW];
    int t = threadIdx.x;
    int gid = blockIdx.x * 256 + t;
    if (gid < n) deg[gid] = 1;                // self-loop contributes 1 in-degree
    for (int i = t; i < 128 * 128; i += 256) {
        int k = i >> 7, c = i & 127;
        WtS[c * LDW + k] = f2b(Wsrc[i]);      // transposed: [col][k]
        WtD[c * LDW + k] = f2b(Wdst[i]);
    }
    __syncthreads();

    int wave = t >> 6, lane = t & 63;
    int r = lane & 15, q = lane >> 4;
    int row = blockIdx.x * 64 + wave * 16 + r;      // A row this lane loads
    f32x4 accS[8], accD[8];
#pragma unroll
    for (int i = 0; i < 8; i++) { accS[i] = (f32x4)(0.f); accD[i] = (f32x4)(0.f); }

#pragma unroll
    for (int kk = 0; kk < 4; kk++) {
        float v[8];
#pragma unroll
        for (int j = 0; j < 8; j++) v[j] = 0.f;
        if (row < n) {
            const float4* src = (const float4*)(x + (long)row * 128 + kk * 32 + q * 8);
            float4 p0 = src[0], p1 = src[1];
            v[0] = p0.x; v[1] = p0.y; v[2] = p0.z; v[3] = p0.w;
            v[4] = p1.x; v[5] = p1.y; v[6] = p1.z; v[7] = p1.w;
        }
        short8 ah, al;
#pragma unroll
        for (int j = 0; j < 8; j++) {
            ushort h = f2b(v[j]);
            ah[j] = (short)h;
            al[j] = (short)f2b(v[j] - b2f(h));
        }
#pragma unroll
        for (int ct = 0; ct < 8; ct++) {
            int off = (ct * 16 + r) * LDW + kk * 32 + q * 8;
            short8 bS = *(const short8*)(WtS + off);
            short8 bD = *(const short8*)(WtD + off);
            accS[ct] = __builtin_amdgcn_mfma_f32_16x16x32_bf16(ah, bS, accS[ct], 0, 0, 0);
            accS[ct] = __builtin_amdgcn_mfma_f32_16x16x32_bf16(al, bS, accS[ct], 0, 0, 0);
            accD[ct] = __builtin_amdgcn_mfma_f32_16x16x32_bf16(ah, bD, accD[ct], 0, 0, 0);
            accD[ct] = __builtin_amdgcn_mfma_f32_16x16x32_bf16(al, bD, accD[ct], 0, 0, 0);
        }
    }
    // C/D layout: col = lane&15, row = (lane>>4)*4 + reg   [m89-verified]
    int rbase = blockIdx.x * 64 + wave * 16 + q * 4;
#pragma unroll
    for (int ct = 0; ct < 8; ct++) {
        int col = ct * 16 + r;
        float bS = bsrc[col];
        float bD = bdst[col];
#pragma unroll
        for (int rg = 0; rg < 4; rg++) {
            int orow = rbase + rg;
            if (orow < n) {
                xs[(long)orow * 128 + col] = accS[ct][rg] + bS;
                xd[(long)orow * 128 + col] = accD[ct][rg] + bD;
            }
        }
    }
}

// ---------------------------------------------------------------------------
// edge_index dtype detector: int64 (little-endian, values < 2^31 => odd 32-bit
// words all zero) vs int32. 64 lanes sample odd words 1..127.
// ---------------------------------------------------------------------------
__global__ void detect_kernel(const int* __restrict__ ei, int* __restrict__ fmt) {
    int lane = threadIdx.x;
    int w = ei[2 * lane + 1];
    unsigned long long nz = __ballot(w != 0);
    if (lane == 0) *fmt = (nz == 0ULL) ? 1 : 0;   // 1 = int64, 0 = int32
}

// ---------------------------------------------------------------------------
// CSR build
// ---------------------------------------------------------------------------
__global__ void count_kernel(const int* __restrict__ ei, int E,
                             int* __restrict__ deg, const int* __restrict__ fmt) {
    int e = blockIdx.x * 256 + threadIdx.x;
    int f = *fmt;
    if (e < E) {
        int d = f ? ei[2 * E + 2 * e] : ei[E + e];
        atomicAdd(&deg[d], 1);
    }
}

// Parallel scan, pass 1: block-local exclusive scan of deg.
__global__ __launch_bounds__(1024) void scan_blk(
    const int* __restrict__ deg, int* __restrict__ lpre,
    int* __restrict__ bsum, int n)
{
    __shared__ int ws[16];
    __shared__ int wp[16];
    int t = threadIdx.x, lane = t & 63, w = t >> 6;
    int g = blockIdx.x * 1024 + t;
    int v = (g < n) ? deg[g] : 0;
    int inc = v;
#pragma unroll
    for (int off = 1; off < 64; off <<= 1) {
        int sh = __shfl_up(inc, off);
        if (lane >= off) inc += sh;
    }
    if (lane == 63) ws[w] = inc;
    __syncthreads();
    if (t == 0) {
        int run = 0;
#pragma unroll
        for (int i = 0; i < 16; i++) { wp[i] = run; run += ws[i]; }
        bsum[blockIdx.x] = run;
    }
    __syncthreads();
    if (g < n) lpre[g] = wp[w] + inc - v;
}

// Parallel scan, pass 2: add preceding block totals, emit row_start + cursor.
__global__ __launch_bounds__(1024) void scan_fix(
    const int* __restrict__ lpre, const int* __restrict__ bsum,
    const int* __restrict__ deg, int* __restrict__ row_start,
    int* __restrict__ cursor, int n)
{
    __shared__ int boff_s;
    int t = threadIdx.x, b = blockIdx.x;
    if (t < 64) {
        int v = 0;
        for (int i = t; i < b; i += 64) v += bsum[i];
#pragma unroll
        for (int off = 32; off >= 1; off >>= 1) v += __shfl_xor(v, off);
        if (t == 0) boff_s = v;
    }
    __syncthreads();
    int g = b * 1024 + t;
    if (g < n) {
        int rs = lpre[g] + boff_s;
        row_start[g] = rs;
        cursor[g] = rs;
        if (g == n - 1) row_start[n] = rs + deg[g];
    }
}

__global__ void fill_kernel(const int* __restrict__ ei, int E, int n,
                            int* __restrict__ cursor, int* __restrict__ esrc,
                            const int* __restrict__ fmt) {
    int idx = blockIdx.x * 256 + threadIdx.x;
    int f = *fmt;
    if (idx < E) {
        int s = f ? ei[2 * idx]         : ei[idx];
        int d = f ? ei[2 * E + 2 * idx] : ei[E + idx];
        int pos = atomicAdd(&cursor[d], 1);
        esrc[pos] = s;
    } else if (idx < E + n) {
        int i = idx - E;
        int pos = atomicAdd(&cursor[i], 1);
        esrc[pos] = i;                  // self-loop
    }
}

// ---------------------------------------------------------------------------
// Fused node kernel: one wave per dst node. Lane l owns channels (2l, 2l+1),
// both in head l>>3. Deferred-max online segment softmax (THR=8) + prefetched
// gather, then residual + LayerNorm + exact GELU. All f32.
// ---------------------------------------------------------------------------
__global__ __launch_bounds__(256) void node_kernel(
    const float* __restrict__ xs, const float* __restrict__ xd,
    const float* __restrict__ x,  const float* __restrict__ att,
    const float* __restrict__ bias_out, const float* __restrict__ gamma,
    const float* __restrict__ beta,
    const int* __restrict__ row_start, const int* __restrict__ esrc,
    float* __restrict__ out, int n)
{
    int lane = threadIdx.x & 63;
    int node = blockIdx.x * 4 + (threadIdx.x >> 6);
    if (node >= n) return;

    float2 dv = ((const float2*)(xd + (long)node * 128))[lane];
    float2 av = ((const float2*)att)[lane];

    int start = row_start[node], end = row_start[node + 1];
    // m = reference max (not necessarily true max); p = exp(r - m) <= e^8.
    float m = -INFINITY, s = 0.f, a0 = 0.f, a1 = 0.f;

    for (int base = start; base < end; base += 64) {
        int cnt = min(64, end - base);
        int jv = (base + lane < end) ? esrc[base + lane] : 0;
        int j0 = __shfl(jv, 0);
        float2 sv = ((const float2*)(xs + (long)j0 * 128))[lane];
        for (int k = 0; k < cnt; k++) {
            // prefetch next edge's row (dup of last edge on final iter — harmless)
            int jn = __shfl(jv, min(k + 1, cnt - 1));
            float2 svn = ((const float2*)(xs + (long)jn * 128))[lane];

            float t0 = sv.x + dv.x;
            float t1 = sv.y + dv.y;
            t0 = fmaxf(t0, 0.f) + 0.2f * fminf(t0, 0.f);   // LeakyReLU(0.2)
            t1 = fmaxf(t1, 0.f) + 0.2f * fminf(t1, 0.f);
            float r = redsum8(t0 * av.x + t1 * av.y);      // head logit

            float d = r - m;
            if (__any(d > 8.f)) {          // rare: raise reference max
                float mn = fmaxf(m, r);
                float cc = __expf(m - mn); // first edge: exp(-inf)=0 zeroes state
                s *= cc; a0 *= cc; a1 *= cc;
                m = mn;
                d = r - m;
            }
            float p = __expf(d);           // bounded by e^8
            s += p;
            a0 = fmaf(p, sv.x, a0);
            a1 = fmaf(p, sv.y, a1);
            sv = svn;
        }
    }

    float inv = 1.f / s;
    float2 bv = ((const float2*)bias_out)[lane];
    float2 xv = ((const float2*)(x + (long)node * 128))[lane];
    float o0 = a0 * inv + bv.x + xv.x;
    float o1 = a1 * inv + bv.y + xv.y;

    float ssum = o0 + o1, ssq = o0 * o0 + o1 * o1;
#pragma unroll
    for (int off = 32; off >= 1; off >>= 1) {
        ssum += __shfl_xor(ssum, off);
        ssq  += __shfl_xor(ssq, off);
    }
    float mean = ssum * (1.f / 128.f);
    float var  = ssq  * (1.f / 128.f) - mean * mean;
    float rstd = rsqrtf(var + 1e-5f);

    float2 gv = ((const float2*)gamma)[lane];
    float2 ev = ((const float2*)beta)[lane];
    float g0 = (o0 - mean) * rstd * gv.x + ev.x;
    float g1 = (o1 - mean) * rstd * gv.y + ev.y;
    g0 = 0.5f * g0 * (1.f + erff(g0 * 0.70710678118654752f));
    g1 = 0.5f * g1 * (1.f + erff(g1 * 0.70710678118654752f));

    float2 res; res.x = g0; res.y = g1;
    ((float2*)(out + (long)node * 128))[lane] = res;
}

// ---------------------------------------------------------------------------
extern "C" void kernel_launch(void* const* d_in, const int* in_sizes, int n_in,
                              void* d_out, int out_size, void* d_ws, size_t ws_size,
                              hipStream_t stream)
{
    const float* x    = (const float*)d_in[0];
    const int*   ei   = (const int*)d_in[1];
    const float* Wsrc = (const float*)d_in[2];
    const float* bsrc = (const float*)d_in[3];
    const float* Wdst = (const float*)d_in[4];
    const float* bdst = (const float*)d_in[5];
    const float* att  = (const float*)d_in[6];
    const float* bout = (const float*)d_in[7];
    const float* gam  = (const float*)d_in[8];
    const float* bet  = (const float*)d_in[9];
    float* out = (float*)d_out;

    int n = in_sizes[0] / 128;
    int E = in_sizes[1] / 2;

    char* p = (char*)d_ws;
    auto alloc = [&](size_t bytes) {
        char* q = p;
        p += (bytes + 255) & ~((size_t)255);
        return q;
    };
    float* xs        = (float*)alloc((size_t)n * 128 * 4);
    float* xd        = (float*)alloc((size_t)n * 128 * 4);
    int*   deg       = (int*)alloc((size_t)n * 4);
    int*   row_start = (int*)alloc((size_t)(n + 1) * 4);
    int*   cursor    = (int*)alloc((size_t)n * 4);
    int*   esrc      = (int*)alloc((size_t)(E + n) * 4);
    int*   fmt       = (int*)alloc(256);
    int    nblk      = (n + 1023) / 1024;
    int*   lpre      = (int*)alloc((size_t)nblk * 1024 * 4);
    int*   bsum      = (int*)alloc((size_t)nblk * 4);

    hipLaunchKernelGGL(detect_kernel, dim3(1), dim3(64), 0, stream, ei, fmt);
    hipLaunchKernelGGL(gemm_kernel, dim3((n + 63) / 64), dim3(256), 0, stream,
                       x, Wsrc, bsrc, Wdst, bdst, xs, xd, n, deg);
    hipLaunchKernelGGL(count_kernel, dim3((E + 255) / 256), dim3(256), 0, stream,
                       ei, E, deg, fmt);
    hipLaunchKernelGGL(scan_blk, dim3(nblk), dim3(1024), 0, stream,
                       deg, lpre, bsum, n);
    hipLaunchKernelGGL(scan_fix, dim3(nblk), dim3(1024), 0, stream,
                       lpre, bsum, deg, row_start, cursor, n);
    hipLaunchKernelGGL(fill_kernel, dim3((E + n + 255) / 256), dim3(256), 0, stream,
                       ei, E, n, cursor, esrc, fmt);
    hipLaunchKernelGGL(node_kernel, dim3((n + 3) / 4), dim3(256), 0, stream,
                       xs, xd, x, att, bout, gam, bet, row_start, esrc, out, n);
}

// Round 10
// 236.168 us; speedup vs baseline: 1.4344x; 1.0586x over previous
//
#include <hip/hip_runtime.h>

typedef unsigned int uint;
typedef unsigned short ushort;
typedef __attribute__((ext_vector_type(8))) short short8;
typedef __attribute__((ext_vector_type(4))) float f32x4;

__device__ __forceinline__ float b2f(ushort u) {
    return __uint_as_float(((uint)u) << 16);
}
__device__ __forceinline__ ushort f2b(float f) {
    uint u = __float_as_uint(f);
    u += 0x7FFFu + ((u >> 16) & 1u);   // round-to-nearest-even
    return (ushort)(u >> 16);
}
__device__ __forceinline__ float fast_exp2(float v) {
    float r;
    asm volatile("v_exp_f32 %0, %1" : "=v"(r) : "v"(v));   // D = 2^S0
    return r;
}

template<int CTRL>
__device__ __forceinline__ float dpp_add(float v) {
    int s = __float_as_int(v);
    int d = __builtin_amdgcn_update_dpp(s, s, CTRL, 0xF, 0xF, true);
    return v + __int_as_float(d);
}
// sum over 8-lane group (lanes sharing l>>3): xor1, xor2, xor7(half-mirror)
__device__ __forceinline__ float redsum8(float t) {
    t = dpp_add<0xB1>(t);    // quad_perm [1,0,3,2]  : lane ^ 1
    t = dpp_add<0x4E>(t);    // quad_perm [2,3,0,1]  : lane ^ 2
    t = dpp_add<0x141>(t);   // row_half_mirror      : lane ^ 7
    return t;
}

// ---------------------------------------------------------------------------
// GEMM: xs = x @ Wsrc + bsrc (bf16 out) ; xd = x @ Wdst + bdst (f32 out)
// MFMA bf16 with x split into hi+lo bf16 (W rounded to bf16 once in LDS).
// ---------------------------------------------------------------------------
#define LDW 136

__global__ __launch_bounds__(256) void gemm_kernel(
    const float* __restrict__ x,
    const float* __restrict__ Wsrc, const float* __restrict__ bsrc,
    const float* __restrict__ Wdst, const float* __restrict__ bdst,
    ushort* __restrict__ xs, float* __restrict__ xd,
    int n, int* __restrict__ deg)
{
    __shared__ ushort WtS[128 * LDW];
    __shared__ ushort WtD[128 * LDW];
    int t = threadIdx.x;
    int gid = blockIdx.x * 256 + t;
    if (gid < n) deg[gid] = 1;                // self-loop contributes 1 in-degree
    for (int i = t; i < 128 * 128; i += 256) {
        int k = i >> 7, c = i & 127;
        WtS[c * LDW + k] = f2b(Wsrc[i]);      // transposed: [col][k]
        WtD[c * LDW + k] = f2b(Wdst[i]);
    }
    __syncthreads();

    int wave = t >> 6, lane = t & 63;
    int r = lane & 15, q = lane >> 4;
    int row = blockIdx.x * 64 + wave * 16 + r;      // A row this lane loads
    f32x4 accS[8], accD[8];
#pragma unroll
    for (int i = 0; i < 8; i++) { accS[i] = (f32x4)(0.f); accD[i] = (f32x4)(0.f); }

#pragma unroll
    for (int kk = 0; kk < 4; kk++) {
        float v[8];
#pragma unroll
        for (int j = 0; j < 8; j++) v[j] = 0.f;
        if (row < n) {
            const float4* src = (const float4*)(x + (long)row * 128 + kk * 32 + q * 8);
            float4 p0 = src[0], p1 = src[1];
            v[0] = p0.x; v[1] = p0.y; v[2] = p0.z; v[3] = p0.w;
            v[4] = p1.x; v[5] = p1.y; v[6] = p1.z; v[7] = p1.w;
        }
        short8 ah, al;
#pragma unroll
        for (int j = 0; j < 8; j++) {
            ushort h = f2b(v[j]);
            ah[j] = (short)h;
            al[j] = (short)f2b(v[j] - b2f(h));
        }
#pragma unroll
        for (int ct = 0; ct < 8; ct++) {
            int off = (ct * 16 + r) * LDW + kk * 32 + q * 8;
            short8 bS = *(const short8*)(WtS + off);
            short8 bD = *(const short8*)(WtD + off);
            accS[ct] = __builtin_amdgcn_mfma_f32_16x16x32_bf16(ah, bS, accS[ct], 0, 0, 0);
            accS[ct] = __builtin_amdgcn_mfma_f32_16x16x32_bf16(al, bS, accS[ct], 0, 0, 0);
            accD[ct] = __builtin_amdgcn_mfma_f32_16x16x32_bf16(ah, bD, accD[ct], 0, 0, 0);
            accD[ct] = __builtin_amdgcn_mfma_f32_16x16x32_bf16(al, bD, accD[ct], 0, 0, 0);
        }
    }
    // C/D layout: col = lane&15, row = (lane>>4)*4 + reg   [m89-verified]
    int rbase = blockIdx.x * 64 + wave * 16 + q * 4;
#pragma unroll
    for (int ct = 0; ct < 8; ct++) {
        int col = ct * 16 + r;
        float bS = bsrc[col];
        float bD = bdst[col];
#pragma unroll
        for (int rg = 0; rg < 4; rg++) {
            int orow = rbase + rg;
            if (orow < n) {
                xs[(long)orow * 128 + col] = f2b(accS[ct][rg] + bS);
                xd[(long)orow * 128 + col] = accD[ct][rg] + bD;
            }
        }
    }
}

// ---------------------------------------------------------------------------
// CSR build. Edge dtype (int64 vs int32) detected per-block: little-endian
// int64 with values < 2^31 has all odd 32-bit words zero.
// ---------------------------------------------------------------------------
__global__ void count_kernel(const int* __restrict__ ei, int E,
                             int* __restrict__ deg) {
    __shared__ int f_s;
    if (threadIdx.x < 64) {
        int w = ei[2 * threadIdx.x + 1];
        unsigned long long nz = __ballot(w != 0);
        if (threadIdx.x == 0) f_s = (nz == 0ULL) ? 1 : 0;
    }
    __syncthreads();
    int f = f_s;
    int e = blockIdx.x * 256 + threadIdx.x;
    if (e < E) {
        int d = f ? ei[2 * E + 2 * e] : ei[E + e];
        atomicAdd(&deg[d], 1);
    }
}

// Parallel scan, pass 1: block-local exclusive scan of deg.
__global__ __launch_bounds__(1024) void scan_blk(
    const int* __restrict__ deg, int* __restrict__ lpre,
    int* __restrict__ bsum, int n)
{
    __shared__ int ws[16];
    __shared__ int wp[16];
    int t = threadIdx.x, lane = t & 63, w = t >> 6;
    int g = blockIdx.x * 1024 + t;
    int v = (g < n) ? deg[g] : 0;
    int inc = v;
#pragma unroll
    for (int off = 1; off < 64; off <<= 1) {
        int sh = __shfl_up(inc, off);
        if (lane >= off) inc += sh;
    }
    if (lane == 63) ws[w] = inc;
    __syncthreads();
    if (t == 0) {
        int run = 0;
#pragma unroll
        for (int i = 0; i < 16; i++) { wp[i] = run; run += ws[i]; }
        bsum[blockIdx.x] = run;
    }
    __syncthreads();
    if (g < n) lpre[g] = wp[w] + inc - v;
}

// Parallel scan, pass 2: add preceding block totals, emit row_start + cursor.
__global__ __launch_bounds__(1024) void scan_fix(
    const int* __restrict__ lpre, const int* __restrict__ bsum,
    const int* __restrict__ deg, int* __restrict__ row_start,
    int* __restrict__ cursor, int n)
{
    __shared__ int boff_s;
    int t = threadIdx.x, b = blockIdx.x;
    if (t < 64) {
        int v = 0;
        for (int i = t; i < b; i += 64) v += bsum[i];
#pragma unroll
        for (int off = 32; off >= 1; off >>= 1) v += __shfl_xor(v, off);
        if (t == 0) boff_s = v;
    }
    __syncthreads();
    int g = b * 1024 + t;
    if (g < n) {
        int rs = lpre[g] + boff_s;
        row_start[g] = rs;
        cursor[g] = rs;
        if (g == n - 1) row_start[n] = rs + deg[g];
    }
}

__global__ void fill_kernel(const int* __restrict__ ei, int E, int n,
                            int* __restrict__ cursor, int* __restrict__ esrc) {
    __shared__ int f_s;
    if (threadIdx.x < 64) {
        int w = ei[2 * threadIdx.x + 1];
        unsigned long long nz = __ballot(w != 0);
        if (threadIdx.x == 0) f_s = (nz == 0ULL) ? 1 : 0;
    }
    __syncthreads();
    int f = f_s;
    int idx = blockIdx.x * 256 + threadIdx.x;
    if (idx < E) {
        int s = f ? ei[2 * idx]         : ei[idx];
        int d = f ? ei[2 * E + 2 * idx] : ei[E + idx];
        int pos = atomicAdd(&cursor[d], 1);
        esrc[pos] = s;
    } else if (idx < E + n) {
        int i = idx - E;
        int pos = atomicAdd(&cursor[i], 1);
        esrc[pos] = i;                  // self-loop
    }
}

// ---------------------------------------------------------------------------
// Fused node kernel: one wave per dst node. Lane l owns channels (2l, 2l+1),
// both in head l>>3. Max-free softmax in exp2 domain (logits ~N(0,2); att
// pre-scaled by log2(e)); 8-deep batched gathers (scalar edge-index loads,
// 8 outstanding row loads). Residual + LayerNorm + exact GELU. f32 out.
// ---------------------------------------------------------------------------
__global__ __launch_bounds__(1024) void node_kernel(
    const ushort* __restrict__ xs, const float* __restrict__ xd,
    const float* __restrict__ x,  const float* __restrict__ att,
    const float* __restrict__ bias_out, const float* __restrict__ gamma,
    const float* __restrict__ beta,
    const int* __restrict__ row_start, const int* __restrict__ esrc,
    float* __restrict__ out, int n)
{
    int lane = threadIdx.x & 63;
    int node = blockIdx.x * 16 + (threadIdx.x >> 6);
    if (node >= n) return;

    float2 dv = ((const float2*)(xd + (long)node * 128))[lane];
    float2 av = ((const float2*)att)[lane];
    const float LOG2E = 1.44269504088896f;
    av.x *= LOG2E; av.y *= LOG2E;          // exp2-domain logits

    int start = row_start[node], end = row_start[node + 1];
    float s = 0.f, a0 = 0.f, a1 = 0.f;

    for (int base = start; base < end; base += 8) {
        int last = end - 1 - base;          // >= 0
        int jj[8];
#pragma unroll
        for (int u = 0; u < 8; u++) jj[u] = esrc[base + min(u, last)];  // uniform -> s_load
        uint raw[8];
#pragma unroll
        for (int u = 0; u < 8; u++)
            raw[u] = ((const uint*)(xs + (long)jj[u] * 128))[lane];     // 8 outstanding gathers
#pragma unroll
        for (int u = 0; u < 8; u++) {
            float v0 = __uint_as_float(raw[u] << 16);
            float v1 = __uint_as_float(raw[u] & 0xFFFF0000u);
            float t0 = v0 + dv.x;
            float t1 = v1 + dv.y;
            t0 = fmaf(0.2f, fminf(t0, 0.f), fmaxf(t0, 0.f));   // LeakyReLU(0.2)
            t1 = fmaf(0.2f, fminf(t1, 0.f), fmaxf(t1, 0.f));
            float r = redsum8(fmaf(t1, av.y, t0 * av.x));      // head logit (log2 dom)
            float p = fast_exp2(fminf(r, 80.f));
            p = (base + u < end) ? p : 0.f;                    // mask tail dups
            s += p;
            a0 = fmaf(p, v0, a0);
            a1 = fmaf(p, v1, a1);
        }
    }

    float inv = 1.f / s;
    float2 bv = ((const float2*)bias_out)[lane];
    float2 xv = ((const float2*)(x + (long)node * 128))[lane];
    float o0 = a0 * inv + bv.x + xv.x;
    float o1 = a1 * inv + bv.y + xv.y;

    float ssum = o0 + o1, ssq = o0 * o0 + o1 * o1;
#pragma unroll
    for (int off = 32; off >= 1; off >>= 1) {
        ssum += __shfl_xor(ssum, off);
        ssq  += __shfl_xor(ssq, off);
    }
    float mean = ssum * (1.f / 128.f);
    float var  = ssq  * (1.f / 128.f) - mean * mean;
    float rstd = rsqrtf(var + 1e-5f);

    float2 gv = ((const float2*)gamma)[lane];
    float2 ev = ((const float2*)beta)[lane];
    float g0 = (o0 - mean) * rstd * gv.x + ev.x;
    float g1 = (o1 - mean) * rstd * gv.y + ev.y;
    g0 = 0.5f * g0 * (1.f + erff(g0 * 0.70710678118654752f));
    g1 = 0.5f * g1 * (1.f + erff(g1 * 0.70710678118654752f));

    float2 res; res.x = g0; res.y = g1;
    ((float2*)(out + (long)node * 128))[lane] = res;
}

// ---------------------------------------------------------------------------
extern "C" void kernel_launch(void* const* d_in, const int* in_sizes, int n_in,
                              void* d_out, int out_size, void* d_ws, size_t ws_size,
                              hipStream_t stream)
{
    const float* x    = (const float*)d_in[0];
    const int*   ei   = (const int*)d_in[1];
    const float* Wsrc = (const float*)d_in[2];
    const float* bsrc = (const float*)d_in[3];
    const float* Wdst = (const float*)d_in[4];
    const float* bdst = (const float*)d_in[5];
    const float* att  = (const float*)d_in[6];
    const float* bout = (const float*)d_in[7];
    const float* gam  = (const float*)d_in[8];
    const float* bet  = (const float*)d_in[9];
    float* out = (float*)d_out;

    int n = in_sizes[0] / 128;
    int E = in_sizes[1] / 2;

    char* p = (char*)d_ws;
    auto alloc = [&](size_t bytes) {
        char* q = p;
        p += (bytes + 255) & ~((size_t)255);
        return q;
    };
    ushort* xs        = (ushort*)alloc((size_t)n * 128 * 2);
    float*  xd        = (float*)alloc((size_t)n * 128 * 4);
    int*    deg       = (int*)alloc((size_t)n * 4);
    int*    row_start = (int*)alloc((size_t)(n + 1) * 4);
    int*    cursor    = (int*)alloc((size_t)n * 4);
    int*    esrc      = (int*)alloc((size_t)(E + n) * 4);
    int     nblk      = (n + 1023) / 1024;
    int*    lpre      = (int*)alloc((size_t)nblk * 1024 * 4);
    int*    bsum      = (int*)alloc((size_t)nblk * 4);

    hipLaunchKernelGGL(gemm_kernel, dim3((n + 63) / 64), dim3(256), 0, stream,
                       x, Wsrc, bsrc, Wdst, bdst, xs, xd, n, deg);
    hipLaunchKernelGGL(count_kernel, dim3((E + 255) / 256), dim3(256), 0, stream,
                       ei, E, deg);
    hipLaunchKernelGGL(scan_blk, dim3(nblk), dim3(1024), 0, stream,
                       deg, lpre, bsum, n);
    hipLaunchKernelGGL(scan_fix, dim3(nblk), dim3(1024), 0, stream,
                       lpre, bsum, deg, row_start, cursor, n);
    hipLaunchKernelGGL(fill_kernel, dim3((E + n + 255) / 256), dim3(256), 0, stream,
                       ei, E, n, cursor, esrc);
    hipLaunchKernelGGL(node_kernel, dim3((n + 15) / 16), dim3(1024), 0, stream,
                       xs, xd, x, att, bout, gam, bet, row_start, esrc, out, n);
}

// Round 11
// 231.360 us; speedup vs baseline: 1.4642x; 1.0208x over previous
//
#include <hip/hip_runtime.h>

typedef unsigned int uint;
typedef unsigned short ushort;
typedef __attribute__((ext_vector_type(8))) short short8;
typedef __attribute__((ext_vector_type(4))) float f32x4;
typedef __attribute__((ext_vector_type(2))) float f32x2;

__device__ __forceinline__ float b2f(ushort u) {
    return __uint_as_float(((uint)u) << 16);
}
__device__ __forceinline__ ushort f2b(float f) {
    uint u = __float_as_uint(f);
    u += 0x7FFFu + ((u >> 16) & 1u);   // round-to-nearest-even
    return (ushort)(u >> 16);
}
__device__ __forceinline__ float fast_exp2(float v) {
    float r;
    asm volatile("v_exp_f32 %0, %1" : "=v"(r) : "v"(v));   // D = 2^S0
    return r;
}
// unpack uint (2 packed bf16) -> f32x2 {lo, hi}
__device__ __forceinline__ f32x2 unpk(uint u) {
    f32x2 o;
    o.x = __uint_as_float(u << 16);
    o.y = __uint_as_float(u & 0xFFFF0000u);
    return o;
}
__device__ __forceinline__ f32x2 pmax0(f32x2 a) {
#if __has_builtin(__builtin_elementwise_max)
    return __builtin_elementwise_max(a, (f32x2)(0.f));
#else
    f32x2 o; o.x = fmaxf(a.x, 0.f); o.y = fmaxf(a.y, 0.f); return o;
#endif
}
__device__ __forceinline__ f32x2 pmin0(f32x2 a) {
#if __has_builtin(__builtin_elementwise_min)
    return __builtin_elementwise_min(a, (f32x2)(0.f));
#else
    f32x2 o; o.x = fminf(a.x, 0.f); o.y = fminf(a.y, 0.f); return o;
#endif
}

template<int CTRL>
__device__ __forceinline__ float dpp_add(float v) {
    int s = __float_as_int(v);
    int d = __builtin_amdgcn_update_dpp(s, s, CTRL, 0xF, 0xF, true);
    return v + __int_as_float(d);
}

// ---------------------------------------------------------------------------
// GEMM: xs = x @ Wsrc + bsrc (bf16 out) ; xd = x @ Wdst + bdst (f32 out)
// MFMA bf16 with x split into hi+lo bf16 (W rounded to bf16 once in LDS).
// ---------------------------------------------------------------------------
#define LDW 136

__global__ __launch_bounds__(256) void gemm_kernel(
    const float* __restrict__ x,
    const float* __restrict__ Wsrc, const float* __restrict__ bsrc,
    const float* __restrict__ Wdst, const float* __restrict__ bdst,
    ushort* __restrict__ xs, float* __restrict__ xd,
    int n, int* __restrict__ deg)
{
    __shared__ ushort WtS[128 * LDW];
    __shared__ ushort WtD[128 * LDW];
    int t = threadIdx.x;
    int gid = blockIdx.x * 256 + t;
    if (gid < n) deg[gid] = 1;                // self-loop contributes 1 in-degree
    for (int i = t; i < 128 * 128; i += 256) {
        int k = i >> 7, c = i & 127;
        WtS[c * LDW + k] = f2b(Wsrc[i]);      // transposed: [col][k]
        WtD[c * LDW + k] = f2b(Wdst[i]);
    }
    __syncthreads();

    int wave = t >> 6, lane = t & 63;
    int r = lane & 15, q = lane >> 4;
    int row = blockIdx.x * 64 + wave * 16 + r;      // A row this lane loads
    f32x4 accS[8], accD[8];
#pragma unroll
    for (int i = 0; i < 8; i++) { accS[i] = (f32x4)(0.f); accD[i] = (f32x4)(0.f); }

#pragma unroll
    for (int kk = 0; kk < 4; kk++) {
        float v[8];
#pragma unroll
        for (int j = 0; j < 8; j++) v[j] = 0.f;
        if (row < n) {
            const float4* src = (const float4*)(x + (long)row * 128 + kk * 32 + q * 8);
            float4 p0 = src[0], p1 = src[1];
            v[0] = p0.x; v[1] = p0.y; v[2] = p0.z; v[3] = p0.w;
            v[4] = p1.x; v[5] = p1.y; v[6] = p1.z; v[7] = p1.w;
        }
        short8 ah, al;
#pragma unroll
        for (int j = 0; j < 8; j++) {
            ushort h = f2b(v[j]);
            ah[j] = (short)h;
            al[j] = (short)f2b(v[j] - b2f(h));
        }
#pragma unroll
        for (int ct = 0; ct < 8; ct++) {
            int off = (ct * 16 + r) * LDW + kk * 32 + q * 8;
            short8 bS = *(const short8*)(WtS + off);
            short8 bD = *(const short8*)(WtD + off);
            accS[ct] = __builtin_amdgcn_mfma_f32_16x16x32_bf16(ah, bS, accS[ct], 0, 0, 0);
            accS[ct] = __builtin_amdgcn_mfma_f32_16x16x32_bf16(al, bS, accS[ct], 0, 0, 0);
            accD[ct] = __builtin_amdgcn_mfma_f32_16x16x32_bf16(ah, bD, accD[ct], 0, 0, 0);
            accD[ct] = __builtin_amdgcn_mfma_f32_16x16x32_bf16(al, bD, accD[ct], 0, 0, 0);
        }
    }
    // C/D layout: col = lane&15, row = (lane>>4)*4 + reg   [m89-verified]
    int rbase = blockIdx.x * 64 + wave * 16 + q * 4;
#pragma unroll
    for (int ct = 0; ct < 8; ct++) {
        int col = ct * 16 + r;
        float bS = bsrc[col];
        float bD = bdst[col];
#pragma unroll
        for (int rg = 0; rg < 4; rg++) {
            int orow = rbase + rg;
            if (orow < n) {
                xs[(long)orow * 128 + col] = f2b(accS[ct][rg] + bS);
                xd[(long)orow * 128 + col] = accD[ct][rg] + bD;
            }
        }
    }
}

// ---------------------------------------------------------------------------
// CSR build. Edge dtype (int64 vs int32) detected per-block: little-endian
// int64 with values < 2^31 has all odd 32-bit words zero.
// ---------------------------------------------------------------------------
__global__ void count_kernel(const int* __restrict__ ei, int E,
                             int* __restrict__ deg) {
    __shared__ int f_s;
    if (threadIdx.x < 64) {
        int w = ei[2 * threadIdx.x + 1];
        unsigned long long nz = __ballot(w != 0);
        if (threadIdx.x == 0) f_s = (nz == 0ULL) ? 1 : 0;
    }
    __syncthreads();
    int f = f_s;
    int e = blockIdx.x * 256 + threadIdx.x;
    if (e < E) {
        int d = f ? ei[2 * E + 2 * e] : ei[E + e];
        atomicAdd(&deg[d], 1);
    }
}

// Parallel scan, pass 1: block-local exclusive scan of deg.
__global__ __launch_bounds__(1024) void scan_blk(
    const int* __restrict__ deg, int* __restrict__ lpre,
    int* __restrict__ bsum, int n)
{
    __shared__ int ws[16];
    __shared__ int wp[16];
    int t = threadIdx.x, lane = t & 63, w = t >> 6;
    int g = blockIdx.x * 1024 + t;
    int v = (g < n) ? deg[g] : 0;
    int inc = v;
#pragma unroll
    for (int off = 1; off < 64; off <<= 1) {
        int sh = __shfl_up(inc, off);
        if (lane >= off) inc += sh;
    }
    if (lane == 63) ws[w] = inc;
    __syncthreads();
    if (t == 0) {
        int run = 0;
#pragma unroll
        for (int i = 0; i < 16; i++) { wp[i] = run; run += ws[i]; }
        bsum[blockIdx.x] = run;
    }
    __syncthreads();
    if (g < n) lpre[g] = wp[w] + inc - v;
}

// Parallel scan, pass 2: add preceding block totals, emit row_start + cursor.
__global__ __launch_bounds__(1024) void scan_fix(
    const int* __restrict__ lpre, const int* __restrict__ bsum,
    const int* __restrict__ deg, int* __restrict__ row_start,
    int* __restrict__ cursor, int n)
{
    __shared__ int boff_s;
    int t = threadIdx.x, b = blockIdx.x;
    if (t < 64) {
        int v = 0;
        for (int i = t; i < b; i += 64) v += bsum[i];
#pragma unroll
        for (int off = 32; off >= 1; off >>= 1) v += __shfl_xor(v, off);
        if (t == 0) boff_s = v;
    }
    __syncthreads();
    int g = b * 1024 + t;
    if (g < n) {
        int rs = lpre[g] + boff_s;
        row_start[g] = rs;
        cursor[g] = rs;
        if (g == n - 1) row_start[n] = rs + deg[g];
    }
}

__global__ void fill_kernel(const int* __restrict__ ei, int E, int n,
                            int* __restrict__ cursor, int* __restrict__ esrc) {
    __shared__ int f_s;
    if (threadIdx.x < 64) {
        int w = ei[2 * threadIdx.x + 1];
        unsigned long long nz = __ballot(w != 0);
        if (threadIdx.x == 0) f_s = (nz == 0ULL) ? 1 : 0;
    }
    __syncthreads();
    int f = f_s;
    int idx = blockIdx.x * 256 + threadIdx.x;
    if (idx < E) {
        int s = f ? ei[2 * idx]         : ei[idx];
        int d = f ? ei[2 * E + 2 * idx] : ei[E + idx];
        int pos = atomicAdd(&cursor[d], 1);
        esrc[pos] = s;
    } else if (idx < E + n) {
        int i = idx - E;
        int pos = atomicAdd(&cursor[i], 1);
        esrc[pos] = i;                  // self-loop
    }
}

// ---------------------------------------------------------------------------
// Fused node kernel v3: one wave per dst node, 4 edges per iteration.
// Quarter q (16 lanes) handles edge base+q; lane r (= lane&15) owns channels
// [r*8, r*8+8) => head r>>1, pair (2h,2h+1) covers head h => 1 DPP pair-sum.
// Packed f32x2 math; max-free exp2-domain softmax (att pre-scaled log2e);
// cross-quarter shfl reduce; residual + LayerNorm + exact GELU epilogue.
// ---------------------------------------------------------------------------
__global__ __launch_bounds__(256) void node_kernel(
    const ushort* __restrict__ xs, const float* __restrict__ xd,
    const float* __restrict__ x,  const float* __restrict__ att,
    const float* __restrict__ bias_out, const float* __restrict__ gamma,
    const float* __restrict__ beta,
    const int* __restrict__ row_start, const int* __restrict__ esrc,
    float* __restrict__ out, int n)
{
    int lane = threadIdx.x & 63;
    int node = blockIdx.x * 4 + (threadIdx.x >> 6);
    if (node >= n) return;
    int q = lane >> 4, r = lane & 15;
    int cb = r * 8;                         // first channel this lane owns

    const float LOG2E = 1.44269504088896f;
    f32x2 xd8[4], at8[4];
    {
        const float4* xp = (const float4*)(xd + (long)node * 128 + cb);
        float4 p0 = xp[0], p1 = xp[1];
        xd8[0].x = p0.x; xd8[0].y = p0.y; xd8[1].x = p0.z; xd8[1].y = p0.w;
        xd8[2].x = p1.x; xd8[2].y = p1.y; xd8[3].x = p1.z; xd8[3].y = p1.w;
        const float4* ap = (const float4*)(att + cb);
        float4 a0 = ap[0], a1 = ap[1];
        at8[0].x = a0.x * LOG2E; at8[0].y = a0.y * LOG2E;
        at8[1].x = a0.z * LOG2E; at8[1].y = a0.w * LOG2E;
        at8[2].x = a1.x * LOG2E; at8[2].y = a1.y * LOG2E;
        at8[3].x = a1.z * LOG2E; at8[3].y = a1.w * LOG2E;
    }

    int start = row_start[node], end = row_start[node + 1];
    int end1 = end - 1;
    f32x2 a8[4];
#pragma unroll
    for (int i = 0; i < 4; i++) a8[i] = (f32x2)(0.f);
    float s = 0.f;

    int j0 = esrc[min(start + q, end1)];
    uint4 raw = *(const uint4*)(xs + (long)j0 * 128 + cb);

    for (int base = start; base < end; base += 4) {
        int jn = esrc[min(base + 4 + q, end1)];
        uint4 rawn = *(const uint4*)(xs + (long)jn * 128 + cb);   // prefetch

        f32x2 v0 = unpk(raw.x), v1 = unpk(raw.y), v2 = unpk(raw.z), v3 = unpk(raw.w);
        f32x2 t0 = v0 + xd8[0], t1 = v1 + xd8[1], t2 = v2 + xd8[2], t3 = v3 + xd8[3];
        t0 = pmax0(t0) + 0.2f * pmin0(t0);      // LeakyReLU(0.2), packed
        t1 = pmax0(t1) + 0.2f * pmin0(t1);
        t2 = pmax0(t2) + 0.2f * pmin0(t2);
        t3 = pmax0(t3) + 0.2f * pmin0(t3);
        f32x2 d2 = t0 * at8[0];
        d2 += t1 * at8[1];
        d2 += t2 * at8[2];
        d2 += t3 * at8[3];
        float d = d2.x + d2.y;
        d = dpp_add<0xB1>(d);                   // pair sum -> head logit (log2 dom)
        float p = fast_exp2(d);
        p = (base + q < end) ? p : 0.f;         // mask tail dups
        s += p;
        a8[0] += p * v0; a8[1] += p * v1; a8[2] += p * v2; a8[3] += p * v3;

        raw = rawn;
    }

    // cross-quarter reduction: lanes {r, r+16, r+32, r+48}
#pragma unroll
    for (int off = 16; off <= 32; off <<= 1) {
        s += __shfl_xor(s, off);
#pragma unroll
        for (int i = 0; i < 4; i++) {
            a8[i].x += __shfl_xor(a8[i].x, off);
            a8[i].y += __shfl_xor(a8[i].y, off);
        }
    }

    // epilogue (quarters hold identical state; reduce within 16 lanes)
    float inv = 1.f / s;
    f32x2 o8[4];
    {
        const float4* bp = (const float4*)(bias_out + cb);
        const float4* xp = (const float4*)(x + (long)node * 128 + cb);
        float4 b0 = bp[0], b1 = bp[1], x0 = xp[0], x1 = xp[1];
        o8[0].x = a8[0].x * inv + b0.x + x0.x; o8[0].y = a8[0].y * inv + b0.y + x0.y;
        o8[1].x = a8[1].x * inv + b0.z + x0.z; o8[1].y = a8[1].y * inv + b0.w + x0.w;
        o8[2].x = a8[2].x * inv + b1.x + x1.x; o8[2].y = a8[2].y * inv + b1.y + x1.y;
        o8[3].x = a8[3].x * inv + b1.z + x1.z; o8[3].y = a8[3].y * inv + b1.w + x1.w;
    }
    float ssum = 0.f, ssq = 0.f;
#pragma unroll
    for (int i = 0; i < 4; i++) {
        ssum += o8[i].x + o8[i].y;
        ssq  += o8[i].x * o8[i].x + o8[i].y * o8[i].y;
    }
#pragma unroll
    for (int off = 1; off <= 8; off <<= 1) {
        ssum += __shfl_xor(ssum, off);
        ssq  += __shfl_xor(ssq, off);
    }
    float mean = ssum * (1.f / 128.f);
    float var  = ssq  * (1.f / 128.f) - mean * mean;
    float rstd = rsqrtf(var + 1e-5f);

    if (q == 0) {
        const float4* gp = (const float4*)(gamma + cb);
        const float4* ep = (const float4*)(beta + cb);
        float4 g0 = gp[0], g1 = gp[1], e0 = ep[0], e1 = ep[1];
        float gch[8] = {g0.x, g0.y, g0.z, g0.w, g1.x, g1.y, g1.z, g1.w};
        float ech[8] = {e0.x, e0.y, e0.z, e0.w, e1.x, e1.y, e1.z, e1.w};
        float och[8] = {o8[0].x, o8[0].y, o8[1].x, o8[1].y,
                        o8[2].x, o8[2].y, o8[3].x, o8[3].y};
        float res[8];
#pragma unroll
        for (int i = 0; i < 8; i++) {
            float g = (och[i] - mean) * rstd * gch[i] + ech[i];
            res[i] = 0.5f * g * (1.f + erff(g * 0.70710678118654752f));
        }
        float4* op = (float4*)(out + (long)node * 128 + cb);
        float4 r0, r1;
        r0.x = res[0]; r0.y = res[1]; r0.z = res[2]; r0.w = res[3];
        r1.x = res[4]; r1.y = res[5]; r1.z = res[6]; r1.w = res[7];
        op[0] = r0; op[1] = r1;
    }
}

// ---------------------------------------------------------------------------
extern "C" void kernel_launch(void* const* d_in, const int* in_sizes, int n_in,
                              void* d_out, int out_size, void* d_ws, size_t ws_size,
                              hipStream_t stream)
{
    const float* x    = (const float*)d_in[0];
    const int*   ei   = (const int*)d_in[1];
    const float* Wsrc = (const float*)d_in[2];
    const float* bsrc = (const float*)d_in[3];
    const float* Wdst = (const float*)d_in[4];
    const float* bdst = (const float*)d_in[5];
    const float* att  = (const float*)d_in[6];
    const float* bout = (const float*)d_in[7];
    const float* gam  = (const float*)d_in[8];
    const float* bet  = (const float*)d_in[9];
    float* out = (float*)d_out;

    int n = in_sizes[0] / 128;
    int E = in_sizes[1] / 2;

    char* p = (char*)d_ws;
    auto alloc = [&](size_t bytes) {
        char* q = p;
        p += (bytes + 255) & ~((size_t)255);
        return q;
    };
    ushort* xs        = (ushort*)alloc((size_t)n * 128 * 2);
    float*  xd        = (float*)alloc((size_t)n * 128 * 4);
    int*    deg       = (int*)alloc((size_t)n * 4);
    int*    row_start = (int*)alloc((size_t)(n + 1) * 4);
    int*    cursor    = (int*)alloc((size_t)n * 4);
    int*    esrc      = (int*)alloc((size_t)(E + n) * 4);
    int     nblk      = (n + 1023) / 1024;
    int*    lpre      = (int*)alloc((size_t)nblk * 1024 * 4);
    int*    bsum      = (int*)alloc((size_t)nblk * 4);

    hipLaunchKernelGGL(gemm_kernel, dim3((n + 63) / 64), dim3(256), 0, stream,
                       x, Wsrc, bsrc, Wdst, bdst, xs, xd, n, deg);
    hipLaunchKernelGGL(count_kernel, dim3((E + 255) / 256), dim3(256), 0, stream,
                       ei, E, deg);
    hipLaunchKernelGGL(scan_blk, dim3(nblk), dim3(1024), 0, stream,
                       deg, lpre, bsum, n);
    hipLaunchKernelGGL(scan_fix, dim3(nblk), dim3(1024), 0, stream,
                       lpre, bsum, deg, row_start, cursor, n);
    hipLaunchKernelGGL(fill_kernel, dim3((E + n + 255) / 256), dim3(256), 0, stream,
                       ei, E, n, cursor, esrc);
    hipLaunchKernelGGL(node_kernel, dim3((n + 3) / 4), dim3(256), 0, stream,
                       xs, xd, x, att, bout, gam, bet, row_start, esrc, out, n);
}

// Round 12
// 221.401 us; speedup vs baseline: 1.5301x; 1.0450x over previous
//
#include <hip/hip_runtime.h>

typedef unsigned int uint;
typedef unsigned short ushort;
typedef __attribute__((ext_vector_type(8))) short short8;
typedef __attribute__((ext_vector_type(4))) float f32x4;

__device__ __forceinline__ float b2f(ushort u) {
    return __uint_as_float(((uint)u) << 16);
}
__device__ __forceinline__ ushort f2b(float f) {
    uint u = __float_as_uint(f);
    u += 0x7FFFu + ((u >> 16) & 1u);   // round-to-nearest-even
    return (ushort)(u >> 16);
}
__device__ __forceinline__ float fast_exp2(float v) {
    float r;
    asm volatile("v_exp_f32 %0, %1" : "=v"(r) : "v"(v));   // D = 2^S0
    return r;
}

template<int CTRL>
__device__ __forceinline__ float dpp_add(float v) {
    int s = __float_as_int(v);
    int d = __builtin_amdgcn_update_dpp(s, s, CTRL, 0xF, 0xF, true);
    return v + __int_as_float(d);
}

// ---------------------------------------------------------------------------
// GEMM: xs = x @ Wsrc + bsrc (bf16 out) ; xd = x @ Wdst + bdst (f32 out)
// MFMA bf16, x split hi+lo bf16. 512 thr (8 waves) = 128 rows/block;
// LDS 69.6 KB -> 2 blocks/CU = 16 waves/CU. float4-vectorized W staging.
// ---------------------------------------------------------------------------
#define LDW 136

__global__ __launch_bounds__(512) void gemm_kernel(
    const float* __restrict__ x,
    const float* __restrict__ Wsrc, const float* __restrict__ bsrc,
    const float* __restrict__ Wdst, const float* __restrict__ bdst,
    ushort* __restrict__ xs, float* __restrict__ xd,
    int n, int* __restrict__ deg)
{
    __shared__ ushort WtS[128 * LDW];
    __shared__ ushort WtD[128 * LDW];
    int t = threadIdx.x;
    int gid = blockIdx.x * 512 + t;
    if (gid < n) deg[gid] = 1;                // self-loop contributes 1 in-degree
    for (int i = t * 4; i < 128 * 128; i += 512 * 4) {
        int k = i >> 7, c = i & 127;
        float4 wS = *(const float4*)(Wsrc + i);
        float4 wD = *(const float4*)(Wdst + i);
        WtS[(c + 0) * LDW + k] = f2b(wS.x);
        WtS[(c + 1) * LDW + k] = f2b(wS.y);
        WtS[(c + 2) * LDW + k] = f2b(wS.z);
        WtS[(c + 3) * LDW + k] = f2b(wS.w);
        WtD[(c + 0) * LDW + k] = f2b(wD.x);
        WtD[(c + 1) * LDW + k] = f2b(wD.y);
        WtD[(c + 2) * LDW + k] = f2b(wD.z);
        WtD[(c + 3) * LDW + k] = f2b(wD.w);
    }
    __syncthreads();

    int wave = t >> 6, lane = t & 63;
    int r = lane & 15, q = lane >> 4;
    int row = blockIdx.x * 128 + wave * 16 + r;     // A row this lane loads
    f32x4 accS[8], accD[8];
#pragma unroll
    for (int i = 0; i < 8; i++) { accS[i] = (f32x4)(0.f); accD[i] = (f32x4)(0.f); }

#pragma unroll
    for (int kk = 0; kk < 4; kk++) {
        float v[8];
#pragma unroll
        for (int j = 0; j < 8; j++) v[j] = 0.f;
        if (row < n) {
            const float4* src = (const float4*)(x + (size_t)row * 128 + kk * 32 + q * 8);
            float4 p0 = src[0], p1 = src[1];
            v[0] = p0.x; v[1] = p0.y; v[2] = p0.z; v[3] = p0.w;
            v[4] = p1.x; v[5] = p1.y; v[6] = p1.z; v[7] = p1.w;
        }
        short8 ah, al;
#pragma unroll
        for (int j = 0; j < 8; j++) {
            ushort h = f2b(v[j]);
            ah[j] = (short)h;
            al[j] = (short)f2b(v[j] - b2f(h));
        }
#pragma unroll
        for (int ct = 0; ct < 8; ct++) {
            int off = (ct * 16 + r) * LDW + kk * 32 + q * 8;
            short8 bS = *(const short8*)(WtS + off);
            short8 bD = *(const short8*)(WtD + off);
            accS[ct] = __builtin_amdgcn_mfma_f32_16x16x32_bf16(ah, bS, accS[ct], 0, 0, 0);
            accS[ct] = __builtin_amdgcn_mfma_f32_16x16x32_bf16(al, bS, accS[ct], 0, 0, 0);
            accD[ct] = __builtin_amdgcn_mfma_f32_16x16x32_bf16(ah, bD, accD[ct], 0, 0, 0);
            accD[ct] = __builtin_amdgcn_mfma_f32_16x16x32_bf16(al, bD, accD[ct], 0, 0, 0);
        }
    }
    // C/D layout: col = lane&15, row = (lane>>4)*4 + reg   [m89-verified]
    int rbase = blockIdx.x * 128 + wave * 16 + q * 4;
#pragma unroll
    for (int ct = 0; ct < 8; ct++) {
        int col = ct * 16 + r;
        float bS = bsrc[col];
        float bD = bdst[col];
#pragma unroll
        for (int rg = 0; rg < 4; rg++) {
            int orow = rbase + rg;
            if (orow < n) {
                xs[(size_t)orow * 128 + col] = f2b(accS[ct][rg] + bS);
                xd[(size_t)orow * 128 + col] = accD[ct][rg] + bD;
            }
        }
    }
}

// ---------------------------------------------------------------------------
// CSR build. Edge dtype (int64 vs int32) detected per-block: little-endian
// int64 with values < 2^31 has all odd 32-bit words zero.
// ---------------------------------------------------------------------------
__global__ void count_kernel(const int* __restrict__ ei, int E,
                             int* __restrict__ deg) {
    __shared__ int f_s;
    if (threadIdx.x < 64) {
        int w = ei[2 * threadIdx.x + 1];
        unsigned long long nz = __ballot(w != 0);
        if (threadIdx.x == 0) f_s = (nz == 0ULL) ? 1 : 0;
    }
    __syncthreads();
    int f = f_s;
    int e = blockIdx.x * 256 + threadIdx.x;
    if (e < E) {
        int d = f ? ei[2 * E + 2 * e] : ei[E + e];
        atomicAdd(&deg[d], 1);
    }
}

// Parallel scan, pass 1: block-local exclusive scan of deg.
__global__ __launch_bounds__(1024) void scan_blk(
    const int* __restrict__ deg, int* __restrict__ lpre,
    int* __restrict__ bsum, int n)
{
    __shared__ int ws[16];
    __shared__ int wp[16];
    int t = threadIdx.x, lane = t & 63, w = t >> 6;
    int g = blockIdx.x * 1024 + t;
    int v = (g < n) ? deg[g] : 0;
    int inc = v;
#pragma unroll
    for (int off = 1; off < 64; off <<= 1) {
        int sh = __shfl_up(inc, off);
        if (lane >= off) inc += sh;
    }
    if (lane == 63) ws[w] = inc;
    __syncthreads();
    if (t == 0) {
        int run = 0;
#pragma unroll
        for (int i = 0; i < 16; i++) { wp[i] = run; run += ws[i]; }
        bsum[blockIdx.x] = run;
    }
    __syncthreads();
    if (g < n) lpre[g] = wp[w] + inc - v;
}

// Parallel scan, pass 2: add preceding block totals, emit row_start + cursor.
__global__ __launch_bounds__(1024) void scan_fix(
    const int* __restrict__ lpre, const int* __restrict__ bsum,
    const int* __restrict__ deg, int* __restrict__ row_start,
    int* __restrict__ cursor, int n)
{
    __shared__ int boff_s;
    int t = threadIdx.x, b = blockIdx.x;
    if (t < 64) {
        int v = 0;
        for (int i = t; i < b; i += 64) v += bsum[i];
#pragma unroll
        for (int off = 32; off >= 1; off >>= 1) v += __shfl_xor(v, off);
        if (t == 0) boff_s = v;
    }
    __syncthreads();
    int g = b * 1024 + t;
    if (g < n) {
        int rs = lpre[g] + boff_s;
        row_start[g] = rs;
        cursor[g] = rs;
        if (g == n - 1) row_start[n] = rs + deg[g];
    }
}

__global__ void fill_kernel(const int* __restrict__ ei, int E, int n,
                            int* __restrict__ cursor, int* __restrict__ esrc) {
    __shared__ int f_s;
    if (threadIdx.x < 64) {
        int w = ei[2 * threadIdx.x + 1];
        unsigned long long nz = __ballot(w != 0);
        if (threadIdx.x == 0) f_s = (nz == 0ULL) ? 1 : 0;
    }
    __syncthreads();
    int f = f_s;
    int idx = blockIdx.x * 256 + threadIdx.x;
    if (idx < E) {
        int s = f ? ei[2 * idx]         : ei[idx];
        int d = f ? ei[2 * E + 2 * idx] : ei[E + idx];
        int pos = atomicAdd(&cursor[d], 1);
        esrc[pos] = s;
    } else if (idx < E + n) {
        int i = idx - E;
        int pos = atomicAdd(&cursor[i], 1);
        esrc[pos] = i;                  // self-loop
    }
}

// ---------------------------------------------------------------------------
// Fused node kernel v4: 1 wave = 1 node (64-thr blocks), 4 edges/iter.
// Quarter q handles edge base+q; lane r = lane&15 owns channels [8r, 8r+8)
// (head r>>1; pair (2m,2m+1) covers head m -> 1 DPP pair-sum per 4 edges).
// leaky(t) = 0.6t + 0.4|t|  =>  logit = 0.6*att.v + 0.4*att.|v+xd| + K,
// K = 0.6*att.xd hoisted per node; exp2-domain; |.| is a free VOP3 modifier.
// ---------------------------------------------------------------------------
__global__ __launch_bounds__(64) void node_kernel(
    const ushort* __restrict__ xs, const float* __restrict__ xd,
    const float* __restrict__ x,  const float* __restrict__ att,
    const float* __restrict__ bias_out, const float* __restrict__ gamma,
    const float* __restrict__ beta,
    const int* __restrict__ row_start, const int* __restrict__ esrc,
    float* __restrict__ out, int n)
{
    int lane = threadIdx.x;
    int node = blockIdx.x;
    if (node >= n) return;
    int q = lane >> 4, r = lane & 15;
    int cb = r * 8;                          // first channel this lane owns

    const float LOG2E = 1.44269504088896f;
    const float A = 0.6f * LOG2E, B = 0.4f * LOG2E;

    float xdc[8], atc[8];
    {
        const float4* xp = (const float4*)(xd + (size_t)node * 128 + cb);
        float4 p0 = xp[0], p1 = xp[1];
        xdc[0]=p0.x; xdc[1]=p0.y; xdc[2]=p0.z; xdc[3]=p0.w;
        xdc[4]=p1.x; xdc[5]=p1.y; xdc[6]=p1.z; xdc[7]=p1.w;
        const float4* ap = (const float4*)(att + cb);
        float4 a0 = ap[0], a1 = ap[1];
        atc[0]=a0.x; atc[1]=a0.y; atc[2]=a0.z; atc[3]=a0.w;
        atc[4]=a1.x; atc[5]=a1.y; atc[6]=a1.z; atc[7]=a1.w;
    }
    float KL = 0.f;
#pragma unroll
    for (int i = 0; i < 8; i++) KL = fmaf(atc[i], xdc[i], KL);
    KL *= A;

    int start = row_start[node], end = row_start[node + 1];
    int end1 = end - 1;
    float s = 0.f, acc[8];
#pragma unroll
    for (int i = 0; i < 8; i++) acc[i] = 0.f;

    uint cboff = (uint)(cb);                 // element offset within row
    int j0 = esrc[min(start + q, end1)];
    uint4 raw = *(const uint4*)(xs + (uint)j0 * 128u + cboff);

    for (int base = start; base < end; base += 4) {
        int jn = esrc[min(base + 4 + q, end1)];
        uint4 rawn = *(const uint4*)(xs + (uint)jn * 128u + cboff);   // prefetch

        float v[8];
        v[0] = __uint_as_float(raw.x << 16); v[1] = __uint_as_float(raw.x & 0xFFFF0000u);
        v[2] = __uint_as_float(raw.y << 16); v[3] = __uint_as_float(raw.y & 0xFFFF0000u);
        v[4] = __uint_as_float(raw.z << 16); v[5] = __uint_as_float(raw.z & 0xFFFF0000u);
        v[6] = __uint_as_float(raw.w << 16); v[7] = __uint_as_float(raw.w & 0xFFFF0000u);

        float dv = 0.f, da = 0.f;
#pragma unroll
        for (int i = 0; i < 8; i++) {
            dv = fmaf(atc[i], v[i], dv);                   // att . v
            da = fmaf(atc[i], fabsf(v[i] + xdc[i]), da);   // att . |v+xd| (abs = free mod)
        }
        float P = fmaf(A, dv, fmaf(B, da, KL));
        P = dpp_add<0xB1>(P);                // pair sum -> head logit (log2 dom)
        float p = fast_exp2(P);
        p = (base + q < end) ? p : 0.f;      // mask tail dups
        s += p;
#pragma unroll
        for (int i = 0; i < 8; i++) acc[i] = fmaf(p, v[i], acc[i]);

        raw = rawn;
    }

    // cross-quarter reduction: lanes {r, r+16, r+32, r+48} (same channels)
#pragma unroll
    for (int off = 16; off <= 32; off <<= 1) {
        s += __shfl_xor(s, off);
#pragma unroll
        for (int i = 0; i < 8; i++) acc[i] += __shfl_xor(acc[i], off);
    }

    // epilogue (quarters hold identical state; LN reduce within 16 lanes)
    float inv = 1.f / s;
    float o[8];
    {
        const float4* bp = (const float4*)(bias_out + cb);
        const float4* xp = (const float4*)(x + (size_t)node * 128 + cb);
        float4 b0 = bp[0], b1 = bp[1], x0 = xp[0], x1 = xp[1];
        o[0] = fmaf(acc[0], inv, b0.x + x0.x); o[1] = fmaf(acc[1], inv, b0.y + x0.y);
        o[2] = fmaf(acc[2], inv, b0.z + x0.z); o[3] = fmaf(acc[3], inv, b0.w + x0.w);
        o[4] = fmaf(acc[4], inv, b1.x + x1.x); o[5] = fmaf(acc[5], inv, b1.y + x1.y);
        o[6] = fmaf(acc[6], inv, b1.z + x1.z); o[7] = fmaf(acc[7], inv, b1.w + x1.w);
    }
    float ssum = 0.f, ssq = 0.f;
#pragma unroll
    for (int i = 0; i < 8; i++) {
        ssum += o[i];
        ssq  = fmaf(o[i], o[i], ssq);
    }
#pragma unroll
    for (int off = 1; off <= 8; off <<= 1) {
        ssum += __shfl_xor(ssum, off);
        ssq  += __shfl_xor(ssq, off);
    }
    float mean = ssum * (1.f / 128.f);
    float var  = ssq  * (1.f / 128.f) - mean * mean;
    float rstd = rsqrtf(var + 1e-5f);

    if (q == 0) {
        const float4* gp = (const float4*)(gamma + cb);
        const float4* ep = (const float4*)(beta + cb);
        float4 g0 = gp[0], g1 = gp[1], e0 = ep[0], e1 = ep[1];
        float gch[8] = {g0.x, g0.y, g0.z, g0.w, g1.x, g1.y, g1.z, g1.w};
        float ech[8] = {e0.x, e0.y, e0.z, e0.w, e1.x, e1.y, e1.z, e1.w};
        float res[8];
#pragma unroll
        for (int i = 0; i < 8; i++) {
            float g = (o[i] - mean) * rstd * gch[i] + ech[i];
            res[i] = 0.5f * g * (1.f + erff(g * 0.70710678118654752f));
        }
        float4* op = (float4*)(out + (size_t)node * 128 + cb);
        float4 r0, r1;
        r0.x = res[0]; r0.y = res[1]; r0.z = res[2]; r0.w = res[3];
        r1.x = res[4]; r1.y = res[5]; r1.z = res[6]; r1.w = res[7];
        op[0] = r0; op[1] = r1;
    }
}

// ---------------------------------------------------------------------------
extern "C" void kernel_launch(void* const* d_in, const int* in_sizes, int n_in,
                              void* d_out, int out_size, void* d_ws, size_t ws_size,
                              hipStream_t stream)
{
    const float* x    = (const float*)d_in[0];
    const int*   ei   = (const int*)d_in[1];
    const float* Wsrc = (const float*)d_in[2];
    const float* bsrc = (const float*)d_in[3];
    const float* Wdst = (const float*)d_in[4];
    const float* bdst = (const float*)d_in[5];
    const float* att  = (const float*)d_in[6];
    const float* bout = (const float*)d_in[7];
    const float* gam  = (const float*)d_in[8];
    const float* bet  = (const float*)d_in[9];
    float* out = (float*)d_out;

    int n = in_sizes[0] / 128;
    int E = in_sizes[1] / 2;

    char* p = (char*)d_ws;
    auto alloc = [&](size_t bytes) {
        char* q = p;
        p += (bytes + 255) & ~((size_t)255);
        return q;
    };
    ushort* xs        = (ushort*)alloc((size_t)n * 128 * 2);
    float*  xd        = (float*)alloc((size_t)n * 128 * 4);
    int*    deg       = (int*)alloc((size_t)n * 4);
    int*    row_start = (int*)alloc((size_t)(n + 1) * 4);
    int*    cursor    = (int*)alloc((size_t)n * 4);
    int*    esrc      = (int*)alloc((size_t)(E + n) * 4);
    int     nblk      = (n + 1023) / 1024;
    int*    lpre      = (int*)alloc((size_t)nblk * 1024 * 4);
    int*    bsum      = (int*)alloc((size_t)nblk * 4);

    hipLaunchKernelGGL(gemm_kernel, dim3((n + 127) / 128), dim3(512), 0, stream,
                       x, Wsrc, bsrc, Wdst, bdst, xs, xd, n, deg);
    hipLaunchKernelGGL(count_kernel, dim3((E + 255) / 256), dim3(256), 0, stream,
                       ei, E, deg);
    hipLaunchKernelGGL(scan_blk, dim3(nblk), dim3(1024), 0, stream,
                       deg, lpre, bsum, n);
    hipLaunchKernelGGL(scan_fix, dim3(nblk), dim3(1024), 0, stream,
                       lpre, bsum, deg, row_start, cursor, n);
    hipLaunchKernelGGL(fill_kernel, dim3((E + n + 255) / 256), dim3(256), 0, stream,
                       ei, E, n, cursor, esrc);
    hipLaunchKernelGGL(node_kernel, dim3(n), dim3(64), 0, stream,
                       xs, xd, x, att, bout, gam, bet, row_start, esrc, out, n);
}